// Round 10
// baseline (151.549 us; speedup 1.0000x reference)
//
#include <hip/hip_runtime.h>
#include <hip/hip_bf16.h>
#include <cstdint>

// Problem constants: B=1024, S=8, H=16, DK=DV=32, D=512
#define NB 1024
#define ND 512
#define NM 8192  // B*S rows

typedef __attribute__((ext_vector_type(8))) short short8;
typedef __attribute__((ext_vector_type(8))) __bf16 bf16x8;
typedef __attribute__((ext_vector_type(4))) float f32x4;
typedef __attribute__((ext_vector_type(4))) unsigned short ushort4v;

__device__ __forceinline__ unsigned short f2bf(float f) {
  uint32_t x = __builtin_bit_cast(uint32_t, f);
  x += 0x7fffu + ((x >> 16) & 1u);  // RNE
  return (unsigned short)(x >> 16);
}
__device__ __forceinline__ float bf2f(unsigned short u) {
  return __builtin_bit_cast(float, (uint32_t)u << 16);
}
__device__ __forceinline__ f32x4 mfma16(short8 a, short8 b, f32x4 c) {
  return __builtin_amdgcn_mfma_f32_16x16x32_bf16(
      __builtin_bit_cast(bf16x8, a), __builtin_bit_cast(bf16x8, b), c, 0, 0, 0);
}
__device__ __forceinline__ short8 cvt8(float4 a, float4 b) {
  short8 r;
  r[0] = (short)f2bf(a.x); r[1] = (short)f2bf(a.y);
  r[2] = (short)f2bf(a.z); r[3] = (short)f2bf(a.w);
  r[4] = (short)f2bf(b.x); r[5] = (short)f2bf(b.y);
  r[6] = (short)f2bf(b.z); r[7] = (short)f2bf(b.w);
  return r;
}

// ---- fp32 -> bf16 pre-convert: weights only (4 x 262144)
__global__ __launch_bounds__(256) void convert_w(
    const float* __restrict__ Wq, const float* __restrict__ Wk,
    const float* __restrict__ Wv, const float* __restrict__ Wo,
    unsigned short* __restrict__ Wqb, unsigned short* __restrict__ Wkb,
    unsigned short* __restrict__ Wvb, unsigned short* __restrict__ Wob) {
  const int idx = blockIdx.x * 256 + threadIdx.x;
  const int sel = idx >> 15, o = (idx & 32767) * 8;
  const float* src = sel == 0 ? Wq : sel == 1 ? Wk : sel == 2 ? Wv : Wo;
  unsigned short* dst = sel == 0 ? Wqb : sel == 1 ? Wkb : sel == 2 ? Wvb : Wob;
  const float4 a = ((const float4*)(src + o))[0];
  const float4 b = ((const float4*)(src + o))[1];
  *(short8*)(dst + o) = cvt8(a, b);
}

// ---- Wave-direct QKV GEMM: NO LDS, NO barriers. Each wave owns a 64x128
// output tile; MFMA fragments load straight from global (A f32, cvt in-reg;
// W bf16). Block = 4 m-stacked waves sharing the same B-panel (L1 reuse).
// Grid 384 = 8 XCDs x 48, chunked swizzle: one A-panel's 12 consumer blocks
// land on one XCD's L2. K-loop: 16 iters of BK=32; A prefetched 1 ahead.
// Fragment layout (verified r1-r9): A/B lane l -> row l&15, k (l>>4)*8..+8;
// C lane l -> col l&15, row (l>>4)*4+r.
__global__ __launch_bounds__(256, 2) void gemm_qkv(
    const float* __restrict__ Qf, const float* __restrict__ Kf,
    const float* __restrict__ Vf,
    const unsigned short* __restrict__ Wqb, const unsigned short* __restrict__ Wkb,
    const unsigned short* __restrict__ Wvb,
    const float* __restrict__ bq, const float* __restrict__ bk,
    const float* __restrict__ bv,
    unsigned short* __restrict__ qo, unsigned short* __restrict__ ko,
    unsigned short* __restrict__ vo) {
  const int bid = blockIdx.x;
  const int lid = (bid & 7) * 48 + (bid >> 3);  // bijective: 384 = 8*48
  const int mgrp = lid / 12, nb = lid % 12;
  const int seg = nb >> 2, nloc = nb & 3;
  const float* A = seg == 0 ? Qf : seg == 1 ? Kf : Vf;
  const unsigned short* W = seg == 0 ? Wqb : seg == 1 ? Wkb : Wvb;
  const float* bias = seg == 0 ? bq : seg == 1 ? bk : bv;
  unsigned short* C = seg == 0 ? qo : seg == 1 ? ko : vo;

  const int tid = threadIdx.x, lane = tid & 63, wid = tid >> 6;
  const int l15 = lane & 15, l4 = lane >> 4;
  const int mBase = mgrp * 256 + wid * 64;
  const int nBase = nloc * 128;

  const float* Arow[4];
  const unsigned short* Wrow[8];
#pragma unroll
  for (int mf = 0; mf < 4; ++mf)
    Arow[mf] = A + (size_t)(mBase + mf * 16 + l15) * ND + l4 * 8;
#pragma unroll
  for (int nf = 0; nf < 8; ++nf)
    Wrow[nf] = W + (size_t)(nBase + nf * 16 + l15) * ND + l4 * 8;

  f32x4 acc[4][8] = {};
  float4 a0[4][2];
#pragma unroll
  for (int mf = 0; mf < 4; ++mf) {
    a0[mf][0] = ((const float4*)Arow[mf])[0];
    a0[mf][1] = ((const float4*)Arow[mf])[1];
  }

  for (int kt = 0; kt < 16; ++kt) {
    // B frags for kt (8 x 1KB loads, L1/L2-served)
    short8 bfr[8];
#pragma unroll
    for (int nf = 0; nf < 8; ++nf)
      bfr[nf] = *(const short8*)(Wrow[nf] + kt * 32);
    // consume current A (cvt overlaps B-load latency)
    short8 af[4];
#pragma unroll
    for (int mf = 0; mf < 4; ++mf) af[mf] = cvt8(a0[mf][0], a0[mf][1]);
    // prefetch next A into the freed buffer (in flight across the MFMAs)
    if (kt < 15) {
#pragma unroll
      for (int mf = 0; mf < 4; ++mf) {
        a0[mf][0] = ((const float4*)(Arow[mf] + (kt + 1) * 32))[0];
        a0[mf][1] = ((const float4*)(Arow[mf] + (kt + 1) * 32))[1];
      }
    }
#pragma unroll
    for (int mf = 0; mf < 4; ++mf)
#pragma unroll
      for (int nf = 0; nf < 8; ++nf)
        acc[mf][nf] = mfma16(af[mf], bfr[nf], acc[mf][nf]);
  }

#pragma unroll
  for (int nf = 0; nf < 8; ++nf) {
    const int gn = nBase + nf * 16 + l15;
    const float bb = bias[gn];
#pragma unroll
    for (int mf = 0; mf < 4; ++mf)
#pragma unroll
      for (int r = 0; r < 4; ++r) {
        const int gm = mBase + mf * 16 + l4 * 4 + r;
        C[(size_t)gm * ND + gn] = f2bf(acc[mf][nf][r] + bb);
      }
  }
}

// ---- Wave-direct Wo GEMM + bias + residual(Q). Wave tile 64x128, A = ctx
// bf16 (direct frag loads, 2-named-buffer prefetch). Grid 128 = 8 x 16.
__global__ __launch_bounds__(256, 2) void gemm_wo(
    const unsigned short* __restrict__ ctx, const unsigned short* __restrict__ Wob,
    const float* __restrict__ bo, const float* __restrict__ Qres,
    float* __restrict__ out) {
  const int bid = blockIdx.x;
  const int lid = (bid & 7) * 16 + (bid >> 3);  // bijective: 128 = 8*16
  const int mgrp = lid >> 2, nloc = lid & 3;
  const int tid = threadIdx.x, lane = tid & 63, wid = tid >> 6;
  const int l15 = lane & 15, l4 = lane >> 4;
  const int mBase = mgrp * 256 + wid * 64;
  const int nBase = nloc * 128;

  const unsigned short* Arow[4];
  const unsigned short* Wrow[8];
#pragma unroll
  for (int mf = 0; mf < 4; ++mf)
    Arow[mf] = ctx + (size_t)(mBase + mf * 16 + l15) * ND + l4 * 8;
#pragma unroll
  for (int nf = 0; nf < 8; ++nf)
    Wrow[nf] = Wob + (size_t)(nBase + nf * 16 + l15) * ND + l4 * 8;

  f32x4 acc[4][8] = {};
  short8 aA[4], aB[4];
#pragma unroll
  for (int mf = 0; mf < 4; ++mf) aA[mf] = *(const short8*)Arow[mf];

  for (int kt = 0; kt < 16; kt += 2) {
#pragma unroll
    for (int mf = 0; mf < 4; ++mf)
      aB[mf] = *(const short8*)(Arow[mf] + (kt + 1) * 32);
    {
      short8 bfr[8];
#pragma unroll
      for (int nf = 0; nf < 8; ++nf)
        bfr[nf] = *(const short8*)(Wrow[nf] + kt * 32);
#pragma unroll
      for (int mf = 0; mf < 4; ++mf)
#pragma unroll
        for (int nf = 0; nf < 8; ++nf)
          acc[mf][nf] = mfma16(aA[mf], bfr[nf], acc[mf][nf]);
    }
    if (kt + 2 < 16) {
#pragma unroll
      for (int mf = 0; mf < 4; ++mf)
        aA[mf] = *(const short8*)(Arow[mf] + (kt + 2) * 32);
    }
    {
      short8 bfr[8];
#pragma unroll
      for (int nf = 0; nf < 8; ++nf)
        bfr[nf] = *(const short8*)(Wrow[nf] + (kt + 1) * 32);
#pragma unroll
      for (int mf = 0; mf < 4; ++mf)
#pragma unroll
        for (int nf = 0; nf < 8; ++nf)
          acc[mf][nf] = mfma16(aB[mf], bfr[nf], acc[mf][nf]);
    }
  }

#pragma unroll
  for (int nf = 0; nf < 8; ++nf) {
    const int gn = nBase + nf * 16 + l15;
    const float bb = bo[gn];
#pragma unroll
    for (int mf = 0; mf < 4; ++mf)
#pragma unroll
      for (int r = 0; r < 4; ++r) {
        const int gm = mBase + mf * 16 + l4 * 4 + r;
        out[(size_t)gm * ND + gn] =
            acc[mf][nf][r] + bb + Qres[(size_t)gm * ND + gn];
      }
  }
}

// ---- attention: one wave per (b,h); lane -> (i=lane>>3, j=lane&7)
__global__ __launch_bounds__(256) void attn_kernel(
    const unsigned short* __restrict__ q, const unsigned short* __restrict__ k,
    const unsigned short* __restrict__ v, const int* __restrict__ mask,
    const float* __restrict__ hyper, float* __restrict__ wout,
    unsigned short* __restrict__ ctx) {
  const int tid = threadIdx.x;
  const int wid = tid >> 6, lane = tid & 63;
  const int t = blockIdx.x * 4 + wid;  // b*16 + h
  const int b = t >> 4, h = t & 15;
  const int i = lane >> 3, j = lane & 7;

  const unsigned short* qrow = q + (size_t)(b * 8 + i) * ND + h * 32;
  const unsigned short* krow = k + (size_t)(b * 8 + j) * ND + h * 32;
  float dot = 0.f;
#pragma unroll
  for (int c = 0; c < 4; ++c) {
    const short8 qv = ((const short8*)qrow)[c];
    const short8 kv = ((const short8*)krow)[c];
#pragma unroll
    for (int e = 0; e < 8; ++e)
      dot += bf2f((unsigned short)qv[e]) * bf2f((unsigned short)kv[e]);
  }
  float score = dot * 0.17677669529663687f;  // 1/sqrt(32)
  if (mask[b * 64 + i * 8 + j]) score = -1e9f;

  float mx = score;
#pragma unroll
  for (int o = 4; o; o >>= 1) mx = fmaxf(mx, __shfl_xor(mx, o, 8));
  const float e = __expf(score - mx);
  float sm = e;
#pragma unroll
  for (int o = 4; o; o >>= 1) sm += __shfl_xor(sm, o, 8);
  const float w = e / sm;
  wout[(size_t)t * 64 + lane] = w;

  const int d0 = (lane & 7) * 4;
  float c0 = 0, c1 = 0, c2 = 0, c3 = 0;
#pragma unroll
  for (int jj = 0; jj < 8; ++jj) {
    const float wj = __shfl(w, jj, 8);
    const ushort4v vv = *(const ushort4v*)(v + (size_t)(b * 8 + jj) * ND + h * 32 + d0);
    c0 += wj * bf2f(vv[0]); c1 += wj * bf2f(vv[1]);
    c2 += wj * bf2f(vv[2]); c3 += wj * bf2f(vv[3]);
  }
  const float4 hv = *(const float4*)(hyper + (size_t)b * 4096 + h * 256 + i * 32 + d0);
  ushort4v co;
  co[0] = f2bf(c0 * hv.x); co[1] = f2bf(c1 * hv.y);
  co[2] = f2bf(c2 * hv.z); co[3] = f2bf(c3 * hv.w);
  *(ushort4v*)(ctx + (size_t)(b * 8 + i) * ND + h * 32 + d0) = co;
}

// ---- in-place: io = LN(io) * g + b  (residual+bias already fused into gemm_wo)
__global__ __launch_bounds__(256) void ln_kernel(float* __restrict__ io,
                                                 const float* __restrict__ g,
                                                 const float* __restrict__ be) {
  const int tid = threadIdx.x, wid = tid >> 6, lane = tid & 63;
  const size_t row = (size_t)blockIdx.x * 4 + wid;
  float* prow = io + row * ND + lane * 8;
  float4 x0 = ((float4*)prow)[0], x1 = ((float4*)prow)[1];
  float s = x0.x + x0.y + x0.z + x0.w + x1.x + x1.y + x1.z + x1.w;
  float sq = x0.x * x0.x + x0.y * x0.y + x0.z * x0.z + x0.w * x0.w +
             x1.x * x1.x + x1.y * x1.y + x1.z * x1.z + x1.w * x1.w;
#pragma unroll
  for (int o = 32; o; o >>= 1) {
    s += __shfl_xor(s, o, 64);
    sq += __shfl_xor(sq, o, 64);
  }
  const float mu = s * (1.f / 512.f);
  const float inv = rsqrtf(sq * (1.f / 512.f) - mu * mu + 1e-5f);
  const float4 g0 = ((const float4*)(g + lane * 8))[0];
  const float4 g1 = ((const float4*)(g + lane * 8))[1];
  const float4 e0 = ((const float4*)(be + lane * 8))[0];
  const float4 e1 = ((const float4*)(be + lane * 8))[1];
  float4 o0, o1;
  o0.x = (x0.x - mu) * inv * g0.x + e0.x; o0.y = (x0.y - mu) * inv * g0.y + e0.y;
  o0.z = (x0.z - mu) * inv * g0.z + e0.z; o0.w = (x0.w - mu) * inv * g0.w + e0.w;
  o1.x = (x1.x - mu) * inv * g1.x + e1.x; o1.y = (x1.y - mu) * inv * g1.y + e1.y;
  o1.z = (x1.z - mu) * inv * g1.z + e1.z; o1.w = (x1.w - mu) * inv * g1.w + e1.w;
  ((float4*)prow)[0] = o0;
  ((float4*)prow)[1] = o1;
}

extern "C" void kernel_launch(void* const* d_in, const int* in_sizes, int n_in,
                              void* d_out, int out_size, void* d_ws, size_t ws_size,
                              hipStream_t stream) {
  const float* Q = (const float*)d_in[0];
  const float* K = (const float*)d_in[1];
  const float* V = (const float*)d_in[2];
  const int* msk = (const int*)d_in[3];
  const float* hyper = (const float*)d_in[4];
  const float* Wq = (const float*)d_in[5];
  const float* bq = (const float*)d_in[6];
  const float* Wk = (const float*)d_in[7];
  const float* bk = (const float*)d_in[8];
  const float* Wv = (const float*)d_in[9];
  const float* bv = (const float*)d_in[10];
  const float* Wo = (const float*)d_in[11];
  const float* bo = (const float*)d_in[12];
  const float* lg = (const float*)d_in[13];
  const float* lb = (const float*)d_in[14];

  float* out = (float*)d_out;           // [8192,512] fp32
  float* wout = out + (size_t)NM * ND;  // [1024,16,8,8] fp32

  const size_t MAT = (size_t)NM * ND;  // elements
  unsigned short* qb = (unsigned short*)d_ws;
  unsigned short* kb = qb + MAT;
  unsigned short* vb = kb + MAT;
  unsigned short* ctxb = vb + MAT;
  unsigned short* Wqb = ctxb + MAT;
  unsigned short* Wkb = Wqb + (size_t)ND * ND;
  unsigned short* Wvb = Wkb + (size_t)ND * ND;
  unsigned short* Wob = Wvb + (size_t)ND * ND;

  convert_w<<<512, 256, 0, stream>>>(Wq, Wk, Wv, Wo, Wqb, Wkb, Wvb, Wob);
  gemm_qkv<<<384, 256, 0, stream>>>(Q, K, V, Wqb, Wkb, Wvb,
                                    bq, bk, bv, qb, kb, vb);
  attn_kernel<<<4096, 256, 0, stream>>>(qb, kb, vb, msk, hyper, wout, ctxb);
  gemm_wo<<<128, 256, 0, stream>>>(ctxb, Wob, bo, Q, out);
  ln_kernel<<<2048, 256, 0, stream>>>(out, lg, lb);
}